// Round 6
// baseline (719.870 us; speedup 1.0000x reference)
//
#include <hip/hip_runtime.h>
#include <hip/hip_bf16.h>

// Problem constants
#define B_ 4
#define S_ 2048
#define E_ 2048
#define H_ 16
#define D_ 128
#define M_ (B_*S_)   // 8192 rows

typedef __attribute__((ext_vector_type(8))) short short8;
typedef __attribute__((ext_vector_type(4))) float f32x4;

__device__ __forceinline__ unsigned short f2bf(float f) {
  union { __hip_bfloat16 h; unsigned short u; } c;
  c.h = __float2bfloat16(f);
  return c.u;
}

__device__ __forceinline__ void gld_lds16(const void* g, void* l) {
  __builtin_amdgcn_global_load_lds((const __attribute__((address_space(1))) void*)g,
                                   (__attribute__((address_space(3))) void*)l, 16, 0, 0);
}

// ---------------- fp32 -> bf16 cast (vectorized) ----------------
__global__ __launch_bounds__(256) void cast_bf16_kernel(const float* __restrict__ in,
                                                        unsigned short* __restrict__ out,
                                                        int n4) {
  int i = blockIdx.x * 256 + threadIdx.x;
  if (i >= n4) return;
  float4 v = ((const float4*)in)[i];
  ushort4 o;
  o.x = f2bf(v.x); o.y = f2bf(v.y); o.z = f2bf(v.z); o.w = f2bf(v.w);
  ((ushort4*)out)[i] = o;
}

// ---------------- GEMM: C[M,N] = A[M,K] @ W[N,K]^T + bias ----------------
// m97 structure: 128x128 tile, BK=32, 4 waves (2x2 of 64x64), global_load_lds w16.
template <typename OutT>
__global__ __launch_bounds__(256) void gemm_bt(const unsigned short* __restrict__ A,
                                               const unsigned short* __restrict__ W,
                                               const float* __restrict__ bias,
                                               OutT* __restrict__ C,
                                               int M, int N, int K) {
  __shared__ unsigned short As[128 * 32];
  __shared__ unsigned short Bs[128 * 32];
  const int tid  = threadIdx.x;
  const int lane = tid & 63;
  const int wid  = tid >> 6;
  const int m0 = blockIdx.y * 128;
  const int n0 = blockIdx.x * 128;
  const int wr = (wid >> 1) * 64;   // wave row offset in tile
  const int wc = (wid & 1) * 64;    // wave col offset in tile
  const int lr  = lane & 15;
  const int lk8 = (lane >> 4) * 8;

  f32x4 acc[4][4];
#pragma unroll
  for (int i = 0; i < 4; i++)
#pragma unroll
    for (int j = 0; j < 4; j++) acc[i][j] = (f32x4){0.f, 0.f, 0.f, 0.f};

  // staging: tile is 128 rows x 32 cols bf16 = 8192 B; 256 thr x 16 B = 4096 B/pass
  const int o0 = tid * 16;            // byte offset in tile, pass 0
  const int row0 = o0 >> 6, colb0 = o0 & 63;
  const int o1 = o0 + 4096;           // pass 1
  const int row1 = o1 >> 6, colb1 = o1 & 63;
  const int ldsb0 = wid * 1024;       // wave-uniform LDS byte base, pass 0
  const int ldsb1 = wid * 1024 + 4096;

  for (int kt = 0; kt < K; kt += 32) {
    gld_lds16(A + (size_t)(m0 + row0) * K + kt + (colb0 >> 1), (char*)As + ldsb0);
    gld_lds16(A + (size_t)(m0 + row1) * K + kt + (colb1 >> 1), (char*)As + ldsb1);
    gld_lds16(W + (size_t)(n0 + row0) * K + kt + (colb0 >> 1), (char*)Bs + ldsb0);
    gld_lds16(W + (size_t)(n0 + row1) * K + kt + (colb1 >> 1), (char*)Bs + ldsb1);
    __syncthreads();

    short8 af[4], bf[4];
#pragma unroll
    for (int i = 0; i < 4; i++) af[i] = *(const short8*)&As[(wr + i * 16 + lr) * 32 + lk8];
#pragma unroll
    for (int j = 0; j < 4; j++) bf[j] = *(const short8*)&Bs[(wc + j * 16 + lr) * 32 + lk8];
#pragma unroll
    for (int i = 0; i < 4; i++)
#pragma unroll
      for (int j = 0; j < 4; j++)
        acc[i][j] = __builtin_amdgcn_mfma_f32_16x16x32_bf16(af[i], bf[j], acc[i][j], 0, 0, 0);
    __syncthreads();
  }

  // epilogue: C/D layout col=lane&15, row=(lane>>4)*4+r  [m89-verified]
#pragma unroll
  for (int i = 0; i < 4; i++) {
    const int gm = m0 + wr + i * 16 + (lane >> 4) * 4;
#pragma unroll
    for (int j = 0; j < 4; j++) {
      const int gn = n0 + wc + j * 16 + lr;
      const float bv = bias[gn];
#pragma unroll
      for (int r = 0; r < 4; r++) {
        const float v = acc[i][j][r] + bv;
        if constexpr (sizeof(OutT) == 2)
          ((unsigned short*)C)[(size_t)(gm + r) * N + gn] = f2bf(v);
        else
          ((float*)C)[(size_t)(gm + r) * N + gn] = v;
      }
    }
  }
}

// ---------------- causal flash attention (folded grid, swapped ops, dual-q) ----------------
// 4 waves (256 thr) per block; each wave owns 32 q rows as TWO 16-row groups
// (A: q0w+lr, B: q0w+16+lr). Block tile = 128 q rows; causal fold pairs tile
// bx with 15-bx -> 68 kv-steps/block, perfectly balanced; grid 8 x H x B.
//
// Key property: K fragments (k0,k1) and V fragments (vb) are read from LDS
// ONCE per step and feed TWO MFMAs each (group A + group B) -> LDS read
// bytes per MFMA halved vs r5 (the measured bottleneck: ~2073 cyc/CU-step
// matched 16 waves x 16KB / 128B/clk LDS bandwidth).
//
// All layouts r5-verified and unchanged:
//   S^T = mfma(kf, qf): lane holds S[kv = kv0+lg*4+r (+16)][qrow = lr-group]
//   Ks[32][128] XOR-swizzled (cb ^= (row&7)<<4) via pre-swizzled gld_lds src
//   Vt[128][32] transposed, chunk-swizzled (write/read pair verified)
//   Plf feed layout [(kv>>3)*128 + q*8 + (kv&7)] per q-group (A at +0, B at +512)
//   O^T lane layout o[d0][r] = O[qrow][d0*16 + lg*4 + r]
// Online softmax with defer-max (T13, THR=8), shared uniform branch.
__global__ __launch_bounds__(256) void flash_attn(const unsigned short* __restrict__ Q,
                                                  const unsigned short* __restrict__ K,
                                                  const unsigned short* __restrict__ V,
                                                  unsigned short* __restrict__ Ctx) {
  __shared__ unsigned short Ks[32 * 128];    // 8 KB, swizzled K tile
  __shared__ unsigned short Vt[128 * 32];    // 8 KB, swizzled V^T tile
  __shared__ unsigned short Pl[4 * 1024];    // 8 KB, per-wave P feed tiles (A+B)

  const int tid  = threadIdx.x;
  const int lane = tid & 63;
  const int wid  = tid >> 6;
  const int lr  = lane & 15;
  const int lg  = lane >> 4;
  const int lk8 = lg * 8;
  const int h  = blockIdx.y;
  const int b  = blockIdx.z;
  const size_t base = ((size_t)b * S_) * E_ + (size_t)h * D_;
  const unsigned short* __restrict__ Kh = K + base;
  const unsigned short* __restrict__ Vh = V + base;
  unsigned short* Plf = Pl + wid * 1024;

  // ---- K staging geometry (per 32x128 tile = 8192 B; 2 passes x 4096 B) ----
  const int oK0 = tid * 16;
  const int rK0 = oK0 >> 8;                 // rows 0..15
  const int cK0 = (oK0 & 255) ^ ((rK0 & 7) << 4);
  const int rK1 = (oK0 + 4096) >> 8;        // rows 16..31
  const int cK1 = (oK0 & 255) ^ ((rK1 & 7) << 4);
  const unsigned short* ksrc0 = Kh + (size_t)rK0 * E_ + (cK0 >> 1);
  const unsigned short* ksrc1 = Kh + (size_t)rK1 * E_ + (cK1 >> 1);
  char* kdst0 = (char*)Ks + wid * 1024;
  char* kdst1 = (char*)Ks + 4096 + wid * 1024;

  // ---- V staging geometry: thread loads 16 u16 of one kv row ----
  const int vr  = tid >> 3;                 // kv row 0..31
  const int c16 = (tid & 7) * 16;           // d base 0..112

  // ---- P feed addresses (per-lane, constant across steps) ----
  const int plw0 = (lg >> 1) * 128 + lr * 8 + (lg & 1) * 4;  // p0 pack (4 u16)
  const int plrd = lg * 128 + lr * 8;                         // B-frag read (16B)

  const float scale = 0.08838834764831845f;  // 1/sqrt(128)

#pragma unroll 1
  for (int half = 0; half < 2; ++half) {
    const int ti = half ? (15 - (int)blockIdx.x) : (int)blockIdx.x;
    const int qblk = ti * 128;              // q-tile base (128 rows)
    const int q0w  = qblk + wid * 32;       // this wave's 32 q rows
    const int qrA  = q0w + lr;              // group A softmax row
    const int qrB  = q0w + 16 + lr;         // group B softmax row

    // ---- Q fragments for both groups ----
    short8 qfA[4], qfB[4];
#pragma unroll
    for (int kk = 0; kk < 4; kk++) {
      qfA[kk] = *(const short8*)&Q[base + (size_t)qrA * E_ + kk * 32 + lk8];
      qfB[kk] = *(const short8*)&Q[base + (size_t)qrB * E_ + kk * 32 + lk8];
    }

    f32x4 oA[8], oB[8];
#pragma unroll
    for (int d0 = 0; d0 < 8; d0++) {
      oA[d0] = (f32x4){0.f, 0.f, 0.f, 0.f};
      oB[d0] = (f32x4){0.f, 0.f, 0.f, 0.f};
    }
    float mA = -INFINITY, mB = -INFINITY;
    float lA = 0.f, lB = 0.f;

    const int nt = (qblk >> 5) + 4;         // (qblk+128)/32 kv steps

    for (int t = 0; t < nt; ++t) {
      const int kv0 = t * 32;
      const size_t koff = (size_t)t * 32 * E_;

      // ---- stage K (async to LDS) + V (reg -> swizzled transpose) ----
      gld_lds16(ksrc0 + koff, kdst0);
      gld_lds16(ksrc1 + koff, kdst1);
      {
        short8 vv0 = *(const short8*)&Vh[koff + (size_t)vr * E_ + c16];
        short8 vv1 = *(const short8*)&Vh[koff + (size_t)vr * E_ + c16 + 8];
#pragma unroll
        for (int j = 0; j < 8; j++) {
          const int d = c16 + j;
          const int sw = ((d >> 1) & 3) ^ ((d >> 4) & 3);
          Vt[d * 32 + (((vr >> 3) ^ sw) << 3) + (vr & 7)] = ((const unsigned short*)&vv0)[j];
        }
#pragma unroll
        for (int j = 0; j < 8; j++) {
          const int d = c16 + 8 + j;
          const int sw = ((d >> 1) & 3) ^ ((d >> 4) & 3);
          Vt[d * 32 + (((vr >> 3) ^ sw) << 3) + (vr & 7)] = ((const unsigned short*)&vv1)[j];
        }
      }
      __syncthreads();   // staged (drains vmcnt for gld_lds + lgkm for ds_writes)

      if (kv0 < q0w + 32) {    // wave has unmasked kv cols this step
        // ---- S^T = K Q^T, both q-groups share each K fragment read ----
        f32x4 s0A = (f32x4){0.f, 0.f, 0.f, 0.f};
        f32x4 s1A = (f32x4){0.f, 0.f, 0.f, 0.f};
        f32x4 s0B = (f32x4){0.f, 0.f, 0.f, 0.f};
        f32x4 s1B = (f32x4){0.f, 0.f, 0.f, 0.f};
        const int swK = (lr & 7) << 4;
#pragma unroll
        for (int kk = 0; kk < 4; kk++) {
          const int cb = (kk * 64 + lg * 16) ^ swK;
          short8 k0 = *(const short8*)((const char*)Ks + lr * 256 + cb);
          short8 k1 = *(const short8*)((const char*)Ks + (16 + lr) * 256 + cb);
          s0A = __builtin_amdgcn_mfma_f32_16x16x32_bf16(k0, qfA[kk], s0A, 0, 0, 0);
          s0B = __builtin_amdgcn_mfma_f32_16x16x32_bf16(k0, qfB[kk], s0B, 0, 0, 0);
          s1A = __builtin_amdgcn_mfma_f32_16x16x32_bf16(k1, qfA[kk], s1A, 0, 0, 0);
          s1B = __builtin_amdgcn_mfma_f32_16x16x32_bf16(k1, qfB[kk], s1B, 0, 0, 0);
        }

        // ---- masked scores; row-reduce in-lane + 2 shuffles per group ----
        const int kvb0 = kv0 + lg * 4;       // s0 kv base
        float v0A[4], v1A[4], v0B[4], v1B[4];
#pragma unroll
        for (int r = 0; r < 4; r++) {
          v0A[r] = (kvb0 + r      <= qrA) ? s0A[r] * scale : -INFINITY;
          v1A[r] = (kvb0 + 16 + r <= qrA) ? s1A[r] * scale : -INFINITY;
          v0B[r] = (kvb0 + r      <= qrB) ? s0B[r] * scale : -INFINITY;
          v1B[r] = (kvb0 + 16 + r <= qrB) ? s1B[r] * scale : -INFINITY;
        }
        float pmA = fmaxf(fmaxf(fmaxf(v0A[0], v0A[1]), fmaxf(v0A[2], v0A[3])),
                          fmaxf(fmaxf(v1A[0], v1A[1]), fmaxf(v1A[2], v1A[3])));
        float pmB = fmaxf(fmaxf(fmaxf(v0B[0], v0B[1]), fmaxf(v0B[2], v0B[3])),
                          fmaxf(fmaxf(v1B[0], v1B[1]), fmaxf(v1B[2], v1B[3])));
        pmA = fmaxf(pmA, __shfl_xor(pmA, 16));
        pmA = fmaxf(pmA, __shfl_xor(pmA, 32));
        pmB = fmaxf(pmB, __shfl_xor(pmB, 16));
        pmB = fmaxf(pmB, __shfl_xor(pmB, 32));

        // ---- online softmax with defer-max (T13, THR=8), shared branch ----
        float p0A[4], p1A[4], p0B[4], p1B[4];
        const float need = fmaxf(pmA - mA, pmB - mB);  // first iter: +inf -> slow
        if (__all(need <= 8.f)) {
          // fast path: keep old max, skip alpha/rescale (P bounded by e^8)
#pragma unroll
          for (int r = 0; r < 4; r++) {
            p0A[r] = __expf(v0A[r] - mA);
            p1A[r] = __expf(v1A[r] - mA);
            p0B[r] = __expf(v0B[r] - mB);
            p1B[r] = __expf(v1B[r] - mB);
          }
          float psA = (p0A[0] + p0A[1]) + (p0A[2] + p0A[3])
                    + (p1A[0] + p1A[1]) + (p1A[2] + p1A[3]);
          float psB = (p0B[0] + p0B[1]) + (p0B[2] + p0B[3])
                    + (p1B[0] + p1B[1]) + (p1B[2] + p1B[3]);
          psA += __shfl_xor(psA, 16); psA += __shfl_xor(psA, 32);
          psB += __shfl_xor(psB, 16); psB += __shfl_xor(psB, 32);
          lA += psA;
          lB += psB;
        } else {
          const float mnA = fmaxf(mA, pmA);
          const float mnB = fmaxf(mB, pmB);
          const float alA = __expf(mA - mnA);   // first iter: exp(-inf)=0
          const float alB = __expf(mB - mnB);
#pragma unroll
          for (int r = 0; r < 4; r++) {
            p0A[r] = __expf(v0A[r] - mnA);
            p1A[r] = __expf(v1A[r] - mnA);
            p0B[r] = __expf(v0B[r] - mnB);
            p1B[r] = __expf(v1B[r] - mnB);
          }
          mA = mnA; mB = mnB;
          float psA = (p0A[0] + p0A[1]) + (p0A[2] + p0A[3])
                    + (p1A[0] + p1A[1]) + (p1A[2] + p1A[3]);
          float psB = (p0B[0] + p0B[1]) + (p0B[2] + p0B[3])
                    + (p1B[0] + p1B[1]) + (p1B[2] + p1B[3]);
          psA += __shfl_xor(psA, 16); psA += __shfl_xor(psA, 32);
          psB += __shfl_xor(psB, 16); psB += __shfl_xor(psB, 32);
          lA = lA * alA + psA;
          lB = lB * alB + psB;
#pragma unroll
          for (int d0 = 0; d0 < 8; ++d0) {
            f32x4 ta = oA[d0], tb = oB[d0];
            ta[0] *= alA; ta[1] *= alA; ta[2] *= alA; ta[3] *= alA;
            tb[0] *= alB; tb[1] *= alB; tb[2] *= alB; tb[3] *= alB;
            oA[d0] = ta; oB[d0] = tb;
          }
        }

        // ---- P -> per-wave feed tiles (packed 8B writes), A at +0, B at +512 ----
        ushort4 wA0, wA1, wB0, wB1;
        wA0.x = f2bf(p0A[0]); wA0.y = f2bf(p0A[1]); wA0.z = f2bf(p0A[2]); wA0.w = f2bf(p0A[3]);
        wA1.x = f2bf(p1A[0]); wA1.y = f2bf(p1A[1]); wA1.z = f2bf(p1A[2]); wA1.w = f2bf(p1A[3]);
        wB0.x = f2bf(p0B[0]); wB0.y = f2bf(p0B[1]); wB0.z = f2bf(p0B[2]); wB0.w = f2bf(p0B[3]);
        wB1.x = f2bf(p1B[0]); wB1.y = f2bf(p1B[1]); wB1.z = f2bf(p1B[2]); wB1.w = f2bf(p1B[3]);
        *(ushort4*)&Plf[plw0]             = wA0;
        *(ushort4*)&Plf[plw0 + 256]       = wA1;
        *(ushort4*)&Plf[512 + plw0]       = wB0;
        *(ushort4*)&Plf[512 + plw0 + 256] = wB1;
        // wave-local data only: drain Plf writes; fence scheduler (rule 18)
        asm volatile("s_waitcnt lgkmcnt(0)" ::: "memory");
        __builtin_amdgcn_sched_barrier(0);

        // ---- O^T += V^T P : each vb read feeds both groups ----
        const short8 pbA = *(const short8*)&Plf[plrd];
        const short8 pbB = *(const short8*)&Plf[512 + plrd];
#pragma unroll
        for (int d0 = 0; d0 < 8; ++d0) {
          const int d = d0 * 16 + lr;
          const int sw = ((d >> 1) & 3) ^ ((d >> 4) & 3);
          const short8 vb = *(const short8*)&Vt[d * 32 + ((lg ^ sw) << 3)];
          oA[d0] = __builtin_amdgcn_mfma_f32_16x16x32_bf16(vb, pbA, oA[d0], 0, 0, 0);
          oB[d0] = __builtin_amdgcn_mfma_f32_16x16x32_bf16(vb, pbB, oB[d0], 0, 0, 0);
        }
      }
      __syncthreads();   // all Ks/Vt reads done before next stage
    }

    // ---- normalize + store ctx (bf16): o[d0][r] = O[qrow][d0*16+lg*4+r] ----
    const float invA = 1.0f / lA;
    const float invB = 1.0f / lB;
    unsigned short* crowA = Ctx + base + (size_t)qrA * E_ + lg * 4;
    unsigned short* crowB = Ctx + base + (size_t)qrB * E_ + lg * 4;
#pragma unroll
    for (int d0 = 0; d0 < 8; ++d0) {
      ushort4 stA, stB;
      stA.x = f2bf(oA[d0][0] * invA);
      stA.y = f2bf(oA[d0][1] * invA);
      stA.z = f2bf(oA[d0][2] * invA);
      stA.w = f2bf(oA[d0][3] * invA);
      stB.x = f2bf(oB[d0][0] * invB);
      stB.y = f2bf(oB[d0][1] * invB);
      stB.z = f2bf(oB[d0][2] * invB);
      stB.w = f2bf(oB[d0][3] * invB);
      *(ushort4*)&crowA[d0 * 16] = stA;
      *(ushort4*)&crowB[d0 * 16] = stB;
    }
  }
}

// ---------------- launcher ----------------
extern "C" void kernel_launch(void* const* d_in, const int* in_sizes, int n_in,
                              void* d_out, int out_size, void* d_ws, size_t ws_size,
                              hipStream_t stream) {
  const float* x  = (const float*)d_in[0];
  // d_in[1] = causal_mask (tril) — implemented analytically
  const float* wq = (const float*)d_in[2];
  const float* bq = (const float*)d_in[3];
  const float* wk = (const float*)d_in[4];
  const float* bk = (const float*)d_in[5];
  const float* wv = (const float*)d_in[6];
  const float* bv = (const float*)d_in[7];
  const float* wo = (const float*)d_in[8];
  const float* bo = (const float*)d_in[9];
  float* out = (float*)d_out;

  char* ws = (char*)d_ws;
  const size_t MB = 1024 * 1024;
  unsigned short* xb  = (unsigned short*)(ws);             // 32 MB
  unsigned short* wqb = (unsigned short*)(ws + 32 * MB);   // 8 MB
  unsigned short* wkb = (unsigned short*)(ws + 40 * MB);   // 8 MB
  unsigned short* wvb = (unsigned short*)(ws + 48 * MB);   // 8 MB
  unsigned short* wob = (unsigned short*)(ws + 56 * MB);   // 8 MB
  unsigned short* Qb  = (unsigned short*)(ws + 64 * MB);   // 32 MB
  unsigned short* Kb  = (unsigned short*)(ws + 96 * MB);   // 32 MB
  unsigned short* Vb  = (unsigned short*)(ws + 128 * MB);  // 32 MB
  unsigned short* Cb  = (unsigned short*)(ws + 160 * MB);  // 32 MB -> 192 MB total

  const int nx4 = M_ * E_ / 4;   // x elements /4
  const int nw4 = E_ * E_ / 4;   // weight elements /4
  cast_bf16_kernel<<<nx4 / 256, 256, 0, stream>>>(x,  xb,  nx4);
  cast_bf16_kernel<<<nw4 / 256, 256, 0, stream>>>(wq, wqb, nw4);
  cast_bf16_kernel<<<nw4 / 256, 256, 0, stream>>>(wk, wkb, nw4);
  cast_bf16_kernel<<<nw4 / 256, 256, 0, stream>>>(wv, wvb, nw4);
  cast_bf16_kernel<<<nw4 / 256, 256, 0, stream>>>(wo, wob, nw4);

  dim3 gg(E_ / 128, M_ / 128);   // (16, 64)
  gemm_bt<unsigned short><<<gg, 256, 0, stream>>>(xb, wqb, bq, Qb, M_, E_, E_);
  gemm_bt<unsigned short><<<gg, 256, 0, stream>>>(xb, wkb, bk, Kb, M_, E_, E_);
  gemm_bt<unsigned short><<<gg, 256, 0, stream>>>(xb, wvb, bv, Vb, M_, E_, E_);

  // folded causal grid: block bx handles 128-row q-tiles bx and 15-bx (68 steps)
  flash_attn<<<dim3(S_ / 128 / 2, H_, B_), 256, 0, stream>>>(Qb, Kb, Vb, Cb);

  gemm_bt<float><<<gg, 256, 0, stream>>>(Cb, wob, bo, out, M_, E_, E_);
}

// Round 7
// 678.690 us; speedup vs baseline: 1.0607x; 1.0607x over previous
//
#include <hip/hip_runtime.h>
#include <hip/hip_bf16.h>

// Problem constants
#define B_ 4
#define S_ 2048
#define E_ 2048
#define H_ 16
#define D_ 128
#define M_ (B_*S_)   // 8192 rows

typedef __attribute__((ext_vector_type(8))) short short8;
typedef __attribute__((ext_vector_type(4))) float f32x4;

__device__ __forceinline__ unsigned short f2bf(float f) {
  union { __hip_bfloat16 h; unsigned short u; } c;
  c.h = __float2bfloat16(f);
  return c.u;
}

__device__ __forceinline__ void gld_lds16(const void* g, void* l) {
  __builtin_amdgcn_global_load_lds((const __attribute__((address_space(1))) void*)g,
                                   (__attribute__((address_space(3))) void*)l, 16, 0, 0);
}

// ---------------- fp32 -> bf16 cast (vectorized) ----------------
__global__ __launch_bounds__(256) void cast_bf16_kernel(const float* __restrict__ in,
                                                        unsigned short* __restrict__ out,
                                                        int n4) {
  int i = blockIdx.x * 256 + threadIdx.x;
  if (i >= n4) return;
  float4 v = ((const float4*)in)[i];
  ushort4 o;
  o.x = f2bf(v.x); o.y = f2bf(v.y); o.z = f2bf(v.z); o.w = f2bf(v.w);
  ((ushort4*)out)[i] = o;
}

// ---------------- GEMM: C[M,N] = A[M,K] @ W[N,K]^T + bias ----------------
// m97 structure: 128x128 tile, BK=32, 4 waves (2x2 of 64x64), global_load_lds w16.
// TR=true: store C^T instead (C_T[N][M]) via swapped-operand MFMA (A-frag of X
// == B-frag of X^T, same lane regs): acc = mfma(bf, af) -> D[n][m] with
// n = lg*4+r, m = lr. Store pattern coalescing identical to TR=false.
template <typename OutT, bool TR = false>
__global__ __launch_bounds__(256) void gemm_bt(const unsigned short* __restrict__ A,
                                               const unsigned short* __restrict__ W,
                                               const float* __restrict__ bias,
                                               OutT* __restrict__ C,
                                               int M, int N, int K) {
  __shared__ unsigned short As[128 * 32];
  __shared__ unsigned short Bs[128 * 32];
  const int tid  = threadIdx.x;
  const int lane = tid & 63;
  const int wid  = tid >> 6;
  const int m0 = blockIdx.y * 128;
  const int n0 = blockIdx.x * 128;
  const int wr = (wid >> 1) * 64;   // wave row offset in tile
  const int wc = (wid & 1) * 64;    // wave col offset in tile
  const int lr  = lane & 15;
  const int lk8 = (lane >> 4) * 8;

  f32x4 acc[4][4];
#pragma unroll
  for (int i = 0; i < 4; i++)
#pragma unroll
    for (int j = 0; j < 4; j++) acc[i][j] = (f32x4){0.f, 0.f, 0.f, 0.f};

  // staging: tile is 128 rows x 32 cols bf16 = 8192 B; 256 thr x 16 B = 4096 B/pass
  const int o0 = tid * 16;            // byte offset in tile, pass 0
  const int row0 = o0 >> 6, colb0 = o0 & 63;
  const int o1 = o0 + 4096;           // pass 1
  const int row1 = o1 >> 6, colb1 = o1 & 63;
  const int ldsb0 = wid * 1024;       // wave-uniform LDS byte base, pass 0
  const int ldsb1 = wid * 1024 + 4096;

  for (int kt = 0; kt < K; kt += 32) {
    gld_lds16(A + (size_t)(m0 + row0) * K + kt + (colb0 >> 1), (char*)As + ldsb0);
    gld_lds16(A + (size_t)(m0 + row1) * K + kt + (colb1 >> 1), (char*)As + ldsb1);
    gld_lds16(W + (size_t)(n0 + row0) * K + kt + (colb0 >> 1), (char*)Bs + ldsb0);
    gld_lds16(W + (size_t)(n0 + row1) * K + kt + (colb1 >> 1), (char*)Bs + ldsb1);
    __syncthreads();

    short8 af[4], bf[4];
#pragma unroll
    for (int i = 0; i < 4; i++) af[i] = *(const short8*)&As[(wr + i * 16 + lr) * 32 + lk8];
#pragma unroll
    for (int j = 0; j < 4; j++) bf[j] = *(const short8*)&Bs[(wc + j * 16 + lr) * 32 + lk8];
#pragma unroll
    for (int i = 0; i < 4; i++)
#pragma unroll
      for (int j = 0; j < 4; j++) {
        if constexpr (TR)
          acc[i][j] = __builtin_amdgcn_mfma_f32_16x16x32_bf16(bf[j], af[i], acc[i][j], 0, 0, 0);
        else
          acc[i][j] = __builtin_amdgcn_mfma_f32_16x16x32_bf16(af[i], bf[j], acc[i][j], 0, 0, 0);
      }
    __syncthreads();
  }

  if constexpr (TR) {
    // C^T epilogue: D[n][m], n = wc+j*16+lg*4+r, m = wr+i*16+lr  [swapped m89]
    const int lg4 = (lane >> 4) * 4;
#pragma unroll
    for (int j = 0; j < 4; j++) {
      const int gn = n0 + wc + j * 16 + lg4;
      const float4 bv4 = *(const float4*)&bias[gn];
#pragma unroll
      for (int i = 0; i < 4; i++) {
        const int gm = m0 + wr + i * 16 + lr;
#pragma unroll
        for (int r = 0; r < 4; r++) {
          const float v = acc[i][j][r] + ((const float*)&bv4)[r];
          ((unsigned short*)C)[(size_t)(gn + r) * M + gm] = f2bf(v);
        }
      }
    }
  } else {
    // epilogue: C/D layout col=lane&15, row=(lane>>4)*4+r  [m89-verified]
#pragma unroll
    for (int i = 0; i < 4; i++) {
      const int gm = m0 + wr + i * 16 + (lane >> 4) * 4;
#pragma unroll
      for (int j = 0; j < 4; j++) {
        const int gn = n0 + wc + j * 16 + lr;
        const float bv = bias[gn];
#pragma unroll
        for (int r = 0; r < 4; r++) {
          const float v = acc[i][j][r] + bv;
          if constexpr (sizeof(OutT) == 2)
            ((unsigned short*)C)[(size_t)(gm + r) * N + gn] = f2bf(v);
          else
            ((float*)C)[(size_t)(gm + r) * N + gn] = v;
        }
      }
    }
  }
}

// ---------------- causal flash attention (folded grid, swapped operands) ----------------
// r5-verified structure: 4 waves (256 thr)/block, wave owns 16 q rows; block
// handles q-tiles bx and 31-bx (66 kv-steps each, perfectly balanced).
// NEW vs r5: V is consumed from the pre-transposed VT[E][M] buffer (written by
// the V-GEMM's TR epilogue) and staged with global_load_lds -- the per-step
// register transpose (2 global loads + 16 ds_write_b16 + ~40 VALU swizzle
// math, and its write-side bank conflicts) is GONE. LDS Vt layout and the
// PV read code are r5-VERBATIM: row d (64 B) holds kv-chunks permuted by
// sw(d) = ((d>>1)&3)^((d>>4)&3); gld_lds dest linear, permutation applied on
// the per-lane GLOBAL source (rule 21), read uses chunk lg^sw(d) as before.
__global__ __launch_bounds__(256) void flash_attn(const unsigned short* __restrict__ Q,
                                                  const unsigned short* __restrict__ K,
                                                  const unsigned short* __restrict__ VT,
                                                  unsigned short* __restrict__ Ctx) {
  __shared__ unsigned short Ks[32 * 128];    // 8 KB, swizzled K tile
  __shared__ unsigned short Vt[128 * 32];    // 8 KB, swizzled V^T tile
  __shared__ unsigned short Pl[4 * 512];     // 4 KB, per-wave P feed tiles

  const int tid  = threadIdx.x;
  const int lane = tid & 63;
  const int wid  = tid >> 6;
  const int lr  = lane & 15;
  const int lg  = lane >> 4;
  const int lk8 = lg * 8;
  const int h  = blockIdx.y;
  const int b  = blockIdx.z;
  const size_t base = ((size_t)b * S_) * E_ + (size_t)h * D_;
  const unsigned short* __restrict__ Kh = K + base;
  // VT head base: row h*D+d, col b*S+kv
  const unsigned short* __restrict__ VTh = VT + (size_t)(h * D_) * M_ + (size_t)b * S_;
  unsigned short* Plf = Pl + wid * 512;

  // ---- K staging geometry (per 32x128 tile = 8192 B; 2 passes x 4096 B) ----
  const int oK0 = tid * 16;
  const int rK0 = oK0 >> 8;                 // rows 0..15
  const int cK0 = (oK0 & 255) ^ ((rK0 & 7) << 4);
  const int rK1 = (oK0 + 4096) >> 8;        // rows 16..31
  const int cK1 = (oK0 & 255) ^ ((rK1 & 7) << 4);
  const unsigned short* ksrc0 = Kh + (size_t)rK0 * E_ + (cK0 >> 1);
  const unsigned short* ksrc1 = Kh + (size_t)rK1 * E_ + (cK1 >> 1);
  char* kdst0 = (char*)Ks + wid * 1024;
  char* kdst1 = (char*)Ks + 4096 + wid * 1024;

  // ---- V^T staging geometry: pass p covers d = p*64 + (tid>>2), chunk tid&3 ----
  // LDS byte offset = d*64 + (tid&3)*16 == tid*16 (linear); global source chunk
  // is (c ^ sw(d)) so LDS row d holds kv-chunk j at chunk j^sw(d) (r5 layout).
  const int dV0 = tid >> 2;                 // 0..63
  const int dV1 = 64 + dV0;                 // 64..127
  const int cV  = tid & 3;
  const int swV0 = ((dV0 >> 1) & 3) ^ ((dV0 >> 4) & 3);
  const int swV1 = ((dV1 >> 1) & 3) ^ ((dV1 >> 4) & 3);
  const unsigned short* vsrc0 = VTh + (size_t)dV0 * M_ + (cV ^ swV0) * 8;
  const unsigned short* vsrc1 = VTh + (size_t)dV1 * M_ + (cV ^ swV1) * 8;
  char* vdst0 = (char*)Vt + wid * 1024;
  char* vdst1 = (char*)Vt + 4096 + wid * 1024;

  // ---- P feed addresses (per-lane, constant across steps) ----
  const int plw0 = (lg >> 1) * 128 + lr * 8 + (lg & 1) * 4;  // p0 pack (4 u16)
  const int plrd = lg * 128 + lr * 8;                         // B-frag read (16B)

  const float scale = 0.08838834764831845f;  // 1/sqrt(128)

#pragma unroll 1
  for (int half = 0; half < 2; ++half) {
    const int ti = half ? (31 - (int)blockIdx.x) : (int)blockIdx.x;
    const int qblk = ti * 64;               // q-tile base
    const int q0w  = qblk + wid * 16;       // this wave's q rows
    const int qrow = q0w + lr;              // this lane's softmax row

    // ---- Q fragments: rows q0w+lr, feature k = kk*32 + lk8 .. +8 ----
    short8 qf[4];
#pragma unroll
    for (int kk = 0; kk < 4; kk++)
      qf[kk] = *(const short8*)&Q[base + (size_t)(q0w + lr) * E_ + kk * 32 + lk8];

    f32x4 o[8];
#pragma unroll
    for (int d0 = 0; d0 < 8; d0++) o[d0] = (f32x4){0.f, 0.f, 0.f, 0.f};
    float mrow = -INFINITY;
    float lsum = 0.f;

    const int nt = (qblk >> 5) + 2;         // (qblk+64)/32 kv steps

    for (int t = 0; t < nt; ++t) {
      const int kv0 = t * 32;
      const size_t koff = (size_t)t * 32 * E_;

      // ---- stage K + V^T (all async global_load_lds; zero staging VALU) ----
      gld_lds16(ksrc0 + koff, kdst0);
      gld_lds16(ksrc1 + koff, kdst1);
      gld_lds16(vsrc0 + kv0, vdst0);
      gld_lds16(vsrc1 + kv0, vdst1);
      __syncthreads();   // barrier drain: staging complete

      if (kv0 < q0w + 16) {    // wave has unmasked kv cols this step
        // ---- S^T = K Q^T : lane holds S[kv0 + lg*4+r (+16)][qrow] ----
        f32x4 s0 = (f32x4){0.f, 0.f, 0.f, 0.f};
        f32x4 s1 = (f32x4){0.f, 0.f, 0.f, 0.f};
        const int swK = (lr & 7) << 4;
#pragma unroll
        for (int kk = 0; kk < 4; kk++) {
          const int cb = (kk * 64 + lg * 16) ^ swK;
          short8 k0 = *(const short8*)((const char*)Ks + lr * 256 + cb);
          short8 k1 = *(const short8*)((const char*)Ks + (16 + lr) * 256 + cb);
          s0 = __builtin_amdgcn_mfma_f32_16x16x32_bf16(k0, qf[kk], s0, 0, 0, 0);
          s1 = __builtin_amdgcn_mfma_f32_16x16x32_bf16(k1, qf[kk], s1, 0, 0, 0);
        }

        // ---- masked scores; row-reduce in-lane + 2 shuffles ----
        const int kvb0 = kv0 + lg * 4;       // s0 kv base
        float v0[4], v1[4];
#pragma unroll
        for (int r = 0; r < 4; r++) {
          v0[r] = (kvb0 + r      <= qrow) ? s0[r] * scale : -INFINITY;
          v1[r] = (kvb0 + 16 + r <= qrow) ? s1[r] * scale : -INFINITY;
        }
        float pm = fmaxf(fmaxf(fmaxf(v0[0], v0[1]), fmaxf(v0[2], v0[3])),
                         fmaxf(fmaxf(v1[0], v1[1]), fmaxf(v1[2], v1[3])));
        pm = fmaxf(pm, __shfl_xor(pm, 16));
        pm = fmaxf(pm, __shfl_xor(pm, 32));

        // ---- online softmax with defer-max (T13, THR=8) ----
        float p0[4], p1[4];
        const float need = pm - mrow;        // first iter: +inf -> slow path
        if (__all(need <= 8.f)) {
          // fast path: keep old max, skip alpha/rescale (P bounded by e^8)
#pragma unroll
          for (int r = 0; r < 4; r++) {
            p0[r] = __expf(v0[r] - mrow);
            p1[r] = __expf(v1[r] - mrow);
          }
          float ps = (p0[0] + p0[1]) + (p0[2] + p0[3])
                   + (p1[0] + p1[1]) + (p1[2] + p1[3]);
          ps += __shfl_xor(ps, 16);
          ps += __shfl_xor(ps, 32);
          lsum += ps;
        } else {
          const float mnew = fmaxf(mrow, pm);
          const float al = __expf(mrow - mnew);   // first iter: exp(-inf)=0
#pragma unroll
          for (int r = 0; r < 4; r++) {
            p0[r] = __expf(v0[r] - mnew);
            p1[r] = __expf(v1[r] - mnew);
          }
          mrow = mnew;
          float ps = (p0[0] + p0[1]) + (p0[2] + p0[3])
                   + (p1[0] + p1[1]) + (p1[2] + p1[3]);
          ps += __shfl_xor(ps, 16);
          ps += __shfl_xor(ps, 32);
          lsum = lsum * al + ps;
#pragma unroll
          for (int d0 = 0; d0 < 8; ++d0) {
            f32x4 tt = o[d0];
            tt[0] *= al; tt[1] *= al; tt[2] *= al; tt[3] *= al;
            o[d0] = tt;
          }
        }

        // ---- P -> per-wave feed tile (two packed 8B writes) ----
        ushort4 w0, w1;
        w0.x = f2bf(p0[0]); w0.y = f2bf(p0[1]); w0.z = f2bf(p0[2]); w0.w = f2bf(p0[3]);
        w1.x = f2bf(p1[0]); w1.y = f2bf(p1[1]); w1.z = f2bf(p1[2]); w1.w = f2bf(p1[3]);
        *(ushort4*)&Plf[plw0]       = w0;
        *(ushort4*)&Plf[plw0 + 256] = w1;
        // wave-local data only: drain Plf writes; fence scheduler (rule 18)
        asm volatile("s_waitcnt lgkmcnt(0)" ::: "memory");
        __builtin_amdgcn_sched_barrier(0);

        // ---- O^T += V^T P : vb = A-frag of V^T (r5-verbatim read) ----
        const short8 pb = *(const short8*)&Plf[plrd];
#pragma unroll
        for (int d0 = 0; d0 < 8; ++d0) {
          const int d = d0 * 16 + lr;
          const int sw = ((d >> 1) & 3) ^ ((d >> 4) & 3);
          const short8 vb = *(const short8*)&Vt[d * 32 + ((lg ^ sw) << 3)];
          o[d0] = __builtin_amdgcn_mfma_f32_16x16x32_bf16(vb, pb, o[d0], 0, 0, 0);
        }
      }
      __syncthreads();   // all Ks/Vt reads done before next stage
    }

    // ---- normalize + store ctx (bf16): o[d0][r] = O[qrow][d0*16+lg*4+r] ----
    const float inv = 1.0f / lsum;
    unsigned short* crow = Ctx + base + (size_t)qrow * E_ + lg * 4;
#pragma unroll
    for (int d0 = 0; d0 < 8; ++d0) {
      ushort4 st;
      st.x = f2bf(o[d0][0] * inv);
      st.y = f2bf(o[d0][1] * inv);
      st.z = f2bf(o[d0][2] * inv);
      st.w = f2bf(o[d0][3] * inv);
      *(ushort4*)&crow[d0 * 16] = st;
    }
  }
}

// ---------------- launcher ----------------
extern "C" void kernel_launch(void* const* d_in, const int* in_sizes, int n_in,
                              void* d_out, int out_size, void* d_ws, size_t ws_size,
                              hipStream_t stream) {
  const float* x  = (const float*)d_in[0];
  // d_in[1] = causal_mask (tril) — implemented analytically
  const float* wq = (const float*)d_in[2];
  const float* bq = (const float*)d_in[3];
  const float* wk = (const float*)d_in[4];
  const float* bk = (const float*)d_in[5];
  const float* wv = (const float*)d_in[6];
  const float* bv = (const float*)d_in[7];
  const float* wo = (const float*)d_in[8];
  const float* bo = (const float*)d_in[9];
  float* out = (float*)d_out;

  char* ws = (char*)d_ws;
  const size_t MB = 1024 * 1024;
  unsigned short* xb  = (unsigned short*)(ws);             // 32 MB
  unsigned short* wqb = (unsigned short*)(ws + 32 * MB);   // 8 MB
  unsigned short* wkb = (unsigned short*)(ws + 40 * MB);   // 8 MB
  unsigned short* wvb = (unsigned short*)(ws + 48 * MB);   // 8 MB
  unsigned short* wob = (unsigned short*)(ws + 56 * MB);   // 8 MB
  unsigned short* Qb  = (unsigned short*)(ws + 64 * MB);   // 32 MB
  unsigned short* Kb  = (unsigned short*)(ws + 96 * MB);   // 32 MB
  unsigned short* VTb = (unsigned short*)(ws + 128 * MB);  // 32 MB, V^T [E][M]
  unsigned short* Cb  = (unsigned short*)(ws + 160 * MB);  // 32 MB -> 192 MB total

  const int nx4 = M_ * E_ / 4;   // x elements /4
  const int nw4 = E_ * E_ / 4;   // weight elements /4
  cast_bf16_kernel<<<nx4 / 256, 256, 0, stream>>>(x,  xb,  nx4);
  cast_bf16_kernel<<<nw4 / 256, 256, 0, stream>>>(wq, wqb, nw4);
  cast_bf16_kernel<<<nw4 / 256, 256, 0, stream>>>(wk, wkb, nw4);
  cast_bf16_kernel<<<nw4 / 256, 256, 0, stream>>>(wv, wvb, nw4);
  cast_bf16_kernel<<<nw4 / 256, 256, 0, stream>>>(wo, wob, nw4);

  dim3 gg(E_ / 128, M_ / 128);   // (16, 64)
  gemm_bt<unsigned short><<<gg, 256, 0, stream>>>(xb, wqb, bq, Qb, M_, E_, E_);
  gemm_bt<unsigned short><<<gg, 256, 0, stream>>>(xb, wkb, bk, Kb, M_, E_, E_);
  // V-projection writes V^T [E][M] directly (swapped-operand TR epilogue)
  gemm_bt<unsigned short, true><<<gg, 256, 0, stream>>>(xb, wvb, bv, VTb, M_, E_, E_);

  // folded causal grid: block bx handles q-tiles bx and 31-bx (66 steps each)
  flash_attn<<<dim3(S_ / 64 / 2, H_, B_), 256, 0, stream>>>(Qb, Kb, VTb, Cb);

  gemm_bt<float><<<gg, 256, 0, stream>>>(Cb, wob, bo, out, M_, E_, E_);
}